// Round 1
// baseline (335.994 us; speedup 1.0000x reference)
//
#include <hip/hip_runtime.h>
#include <math.h>

#define B_    4
#define DIM_  96
#define L_    4096
#define DI_   192   // DINNER
#define DS_   16    // DSTATE
#define NCH_  32    // chunks for scan
#define CHL_  128   // L_/NCH_

// ---------------- K1: grouped 3x3 conv (pad 1) + BN stat accumulation ----------------
__global__ __launch_bounds__(256) void k1_conv_bn(
    const float* __restrict__ x1, const float* __restrict__ x2,
    const float* __restrict__ cw, const float* __restrict__ cb,
    float* __restrict__ y_raw, float* __restrict__ bnsum, float* __restrict__ bnsq)
{
    int bid  = blockIdx.x;            // b*96*16 + c*16 + tile
    int tile = bid & 15;
    int c    = (bid >> 4) % 96;
    int b    = bid / (16 * 96);
    int p    = tile * 256 + threadIdx.x;   // 0..4095
    int i    = p >> 6, j = p & 63;

    const float* src;
    if (c < 64) src = x1 + ((size_t)(b * 192 + 3 * c)) * L_;
    else        src = x2 + ((size_t)(b * 96 + (3 * c - 192))) * L_;
    const float* wp = cw + c * 27;

    float acc = cb[c];
    #pragma unroll
    for (int g = 0; g < 3; ++g) {
        const float* sg = src + g * L_;
        #pragma unroll
        for (int di = 0; di < 3; ++di) {
            int ii = i + di - 1;
            if (ii < 0 || ii > 63) continue;
            #pragma unroll
            for (int dj = 0; dj < 3; ++dj) {
                int jj = j + dj - 1;
                if (jj < 0 || jj > 63) continue;
                acc += sg[ii * 64 + jj] * wp[(g * 3 + di) * 3 + dj];
            }
        }
    }
    y_raw[((size_t)(b * 96 + c)) * L_ + p] = acc;

    // block reduction of sum / sumsq, then one atomic each
    float s1 = acc, s2 = acc * acc;
    for (int m = 32; m; m >>= 1) { s1 += __shfl_down(s1, m); s2 += __shfl_down(s2, m); }
    __shared__ float ls1[4], ls2[4];
    int wid = threadIdx.x >> 6, lane = threadIdx.x & 63;
    if (lane == 0) { ls1[wid] = s1; ls2[wid] = s2; }
    __syncthreads();
    if (threadIdx.x == 0) {
        float a1 = ls1[0] + ls1[1] + ls1[2] + ls1[3];
        float a2 = ls2[0] + ls2[1] + ls2[2] + ls2[3];
        atomicAdd(&bnsum[c], a1);
        atomicAdd(&bnsq[c],  a2);
    }
}

// ---------------- K2: finalize BN scale/shift ----------------
__global__ void k2_bn_fin(const float* __restrict__ bnsum, const float* __restrict__ bnsq,
                          const float* __restrict__ bng, const float* __restrict__ bnb,
                          float* __restrict__ scale, float* __restrict__ shift)
{
    int c = threadIdx.x;
    if (c < 96) {
        float mean = bnsum[c] * (1.0f / 16384.0f);
        float var  = bnsq[c] * (1.0f / 16384.0f) - mean * mean;
        float rstd = rsqrtf(var + 1e-5f);
        float sc = bng[c] * rstd;
        scale[c] = sc;
        shift[c] = bnb[c] - mean * sc;
    }
}

// ---------------- K3: LayerNorm(96) + in_proj (96 -> 384), split into xs/z ----------------
__global__ __launch_bounds__(256) void k3_ln_inproj(
    const float* __restrict__ x2, const float* __restrict__ lng, const float* __restrict__ lnb,
    const float* __restrict__ Wip, float* __restrict__ xs_t, float* __restrict__ z_t)
{
    __shared__ float un[16][97];
    int bid = blockIdx.x;           // b*256 + lt
    int lt  = bid & 255;
    int b   = bid >> 8;
    int l0  = lt * 16;
    int tid = threadIdx.x;

    for (int q = tid; q < 96 * 16; q += 256) {
        int c = q >> 4, t = q & 15;
        un[t][c] = x2[((size_t)(b * 96 + c)) * L_ + l0 + t];
    }
    __syncthreads();

    // per-l LN stats: 16 lanes per l
    int l = tid >> 4, sub = tid & 15;
    float s = 0.f, ss = 0.f;
    #pragma unroll
    for (int k = 0; k < 6; ++k) { float v = un[l][sub + 16 * k]; s += v; ss += v * v; }
    #pragma unroll
    for (int m = 1; m < 16; m <<= 1) { s += __shfl_xor(s, m); ss += __shfl_xor(ss, m); }
    float mean = s * (1.0f / 96.0f);
    float var  = ss * (1.0f / 96.0f) - mean * mean;
    float rstd = rsqrtf(var + 1e-6f);
    #pragma unroll
    for (int k = 0; k < 6; ++k) {
        int c = sub + 16 * k;
        un[l][c] = (un[l][c] - mean) * rstd * lng[c] + lnb[c];
    }
    __syncthreads();

    // GEMM: each thread -> one l (t&15) and 24 columns (colset + 16*j)
    int l2 = tid & 15, colset = tid >> 4;
    for (int j = 0; j < 24; ++j) {
        int col = colset + 16 * j;
        const float* wr = Wip + col * 96;
        float acc = 0.f;
        #pragma unroll 8
        for (int c = 0; c < 96; ++c) acc += un[l2][c] * wr[c];
        if (col < 192) xs_t[((size_t)(b * 192 + col)) * L_ + l0 + l2] = acc;
        else           z_t [((size_t)(b * 192 + col - 192)) * L_ + l0 + l2] = acc;
    }
}

// ---------------- K4: causal conv1d(k=4)+SiLU, x_proj (192->38), dt_proj+softplus ----------------
__global__ __launch_bounds__(256) void k4_conv1d_xproj(
    const float* __restrict__ xs_t, const float* __restrict__ w1, const float* __restrict__ b1,
    const float* __restrict__ Wxp, const float* __restrict__ Wdt, const float* __restrict__ bdt,
    float* __restrict__ xss_t, float* __restrict__ dt_t,
    float* __restrict__ Bm, float* __restrict__ Cm)
{
    __shared__ float xc [192][20];   // 19 used (halo 3)
    __shared__ float xss[192][17];
    __shared__ float dbl[38][17];
    int bid = blockIdx.x;
    int lt  = bid & 255;
    int b   = bid >> 8;
    int l0  = lt * 16;
    int tid = threadIdx.x;

    for (int q = tid; q < 192 * 19; q += 256) {
        int d = q / 19, t = q % 19;
        int l = l0 - 3 + t;
        xc[d][t] = (l >= 0) ? xs_t[((size_t)(b * 192 + d)) * L_ + l] : 0.f;
    }
    __syncthreads();

    for (int q = tid; q < 192 * 16; q += 256) {
        int d = q >> 4, t = q & 15;
        float acc = b1[d];
        #pragma unroll
        for (int k = 0; k < 4; ++k) acc += xc[d][t + k] * w1[d * 4 + k];
        acc = acc / (1.f + expf(-acc));  // SiLU
        xss[d][t] = acc;
        xss_t[((size_t)(b * 192 + d)) * L_ + l0 + t] = acc;
    }
    __syncthreads();

    for (int q = tid; q < 38 * 16; q += 256) {
        int col = q >> 4, t = q & 15;
        const float* wr = Wxp + col * 192;
        float acc = 0.f;
        #pragma unroll 8
        for (int d = 0; d < 192; ++d) acc += xss[d][t] * wr[d];
        dbl[col][t] = acc;
    }
    __syncthreads();

    for (int q = tid; q < 192 * 16; q += 256) {
        int d = q >> 4, t = q & 15;
        float acc = bdt[d];
        #pragma unroll
        for (int r = 0; r < 6; ++r) acc += dbl[r][t] * Wdt[d * 6 + r];
        acc = (acc > 20.f) ? acc : log1pf(expf(acc));   // softplus
        dt_t[((size_t)(b * 192 + d)) * L_ + l0 + t] = acc;
    }
    // B and C matrices: [b][l][n] layout (n fastest -> coalesced)
    {
        int q = tid;
        if (q < 256) {
            int n = q & 15, t = q >> 4;
            Bm[((size_t)(b * L_) + l0 + t) * 16 + n] = dbl[6 + n][t];
            Cm[((size_t)(b * L_) + l0 + t) * 16 + n] = dbl[22 + n][t];
        }
    }
}

// ---------------- K5: scan phase A (per-chunk partial h and cumulative product) ----------------
__global__ __launch_bounds__(256) void k5_scan_partial(
    const float* __restrict__ dt_t, const float* __restrict__ xss_t, const float* __restrict__ Bm,
    const float* __restrict__ A_log, float* __restrict__ hpart, float* __restrict__ Pprod)
{
    int gtid  = blockIdx.x * 256 + threadIdx.x;
    int n     = gtid & 15;
    int gid   = gtid >> 4;          // (b*192+d)*32 + chunk
    int chunk = gid & 31;
    int bd    = gid >> 5;
    int d     = bd % DI_;
    int b     = bd / DI_;
    float a = -expf(A_log[d * 16 + n]);
    const float* dtp = dt_t  + (size_t)bd * L_ + chunk * CHL_;
    const float* xsp = xss_t + (size_t)bd * L_ + chunk * CHL_;
    const float* Bp  = Bm + ((size_t)b * L_ + chunk * CHL_) * 16 + n;
    float h = 0.f, P = 1.f;
    for (int i = 0; i < CHL_; ++i) {
        float dt = dtp[i];
        float xv = xsp[i];
        float Bv = Bp[i * 16];
        float dA = expf(dt * a);
        h = dA * h + dt * Bv * xv;
        P *= dA;
    }
    int idx = chunk * (B_ * DI_ * DS_) + bd * 16 + n;
    hpart[idx] = h;
    Pprod[idx] = P;
}

// ---------------- K6: sequential combine over chunks (32 steps) ----------------
__global__ void k6_combine(const float* __restrict__ hpart, const float* __restrict__ Pprod,
                           float* __restrict__ H0)
{
    int j = blockIdx.x * 256 + threadIdx.x;   // < 12288
    float H = 0.f;
    #pragma unroll
    for (int c = 0; c < NCH_; ++c) {
        int idx = c * (B_ * DI_ * DS_) + j;
        H0[idx] = H;
        H = Pprod[idx] * H + hpart[idx];
    }
}

// ---------------- K7: scan phase C (replay with h0, fuse D-skip + SiLU(z) gate) ----------------
__global__ __launch_bounds__(256) void k7_scan_final(
    const float* __restrict__ dt_t, const float* __restrict__ xss_t, const float* __restrict__ Bm,
    const float* __restrict__ Cm, const float* __restrict__ z_t, const float* __restrict__ A_log,
    const float* __restrict__ Dp, const float* __restrict__ H0, float* __restrict__ g_t)
{
    int gtid  = blockIdx.x * 256 + threadIdx.x;
    int n     = gtid & 15;
    int gid   = gtid >> 4;
    int chunk = gid & 31;
    int bd    = gid >> 5;
    int d     = bd % DI_;
    int b     = bd / DI_;
    float a  = -expf(A_log[d * 16 + n]);
    float Dv = Dp[d];
    const float* dtp = dt_t  + (size_t)bd * L_ + chunk * CHL_;
    const float* xsp = xss_t + (size_t)bd * L_ + chunk * CHL_;
    const float* zp  = z_t   + (size_t)bd * L_ + chunk * CHL_;
    const float* Bp  = Bm + ((size_t)b * L_ + chunk * CHL_) * 16 + n;
    const float* Cp  = Cm + ((size_t)b * L_ + chunk * CHL_) * 16 + n;
    float h = H0[chunk * (B_ * DI_ * DS_) + bd * 16 + n];
    float* gp = g_t + (size_t)bd * L_ + chunk * CHL_;
    for (int i = 0; i < CHL_; ++i) {
        float dt = dtp[i];
        float xv = xsp[i];
        float dA = expf(dt * a);
        h = dA * h + dt * Bp[i * 16] * xv;
        float y = h * Cp[i * 16];
        y += __shfl_xor(y, 1); y += __shfl_xor(y, 2);
        y += __shfl_xor(y, 4); y += __shfl_xor(y, 8);
        if (n == 0) {
            float zv = zp[i];
            float sz = zv / (1.f + expf(-zv));
            gp[i] = (y + xv * Dv) * sz;
        }
    }
}

// ---------------- K8: out_proj (192->96) + BN residual + grouped 1x1 down conv ----------------
__global__ __launch_bounds__(256) void k8_out(
    const float* __restrict__ g_t, const float* __restrict__ Wout,
    const float* __restrict__ y_raw, const float* __restrict__ scale, const float* __restrict__ shift,
    const float* __restrict__ dw, float* __restrict__ out)
{
    __shared__ float gs[192][17];
    __shared__ float os[96][17];
    int bid = blockIdx.x;
    int lt  = bid & 255;
    int b   = bid >> 8;
    int l0  = lt * 16;
    int tid = threadIdx.x;

    for (int q = tid; q < 192 * 16; q += 256) {
        int d = q >> 4, t = q & 15;
        gs[d][t] = g_t[((size_t)(b * 192 + d)) * L_ + l0 + t];
    }
    __syncthreads();

    for (int q = tid; q < 96 * 16; q += 256) {
        int c = q >> 4, t = q & 15;
        const float* wr = Wout + c * 192;
        float acc = 0.f;
        #pragma unroll 8
        for (int d = 0; d < 192; ++d) acc += gs[d][t] * wr[d];
        acc += y_raw[((size_t)(b * 96 + c)) * L_ + l0 + t] * scale[c] + shift[c];
        os[c][t] = acc;
    }
    __syncthreads();

    for (int q = tid; q < 48 * 16; q += 256) {
        int o = q >> 4, t = q & 15;
        out[((size_t)(b * 48 + o)) * L_ + l0 + t] = os[2 * o][t] * dw[2 * o] + os[2 * o + 1][t] * dw[2 * o + 1];
    }
}

// ---------------- launch ----------------
extern "C" void kernel_launch(void* const* d_in, const int* in_sizes, int n_in,
                              void* d_out, int out_size, void* d_ws, size_t ws_size,
                              hipStream_t stream)
{
    const float* x1     = (const float*)d_in[0];
    const float* x2     = (const float*)d_in[1];
    const float* conv_w = (const float*)d_in[2];
    const float* conv_b = (const float*)d_in[3];
    const float* bn_g   = (const float*)d_in[4];
    const float* bn_b   = (const float*)d_in[5];
    const float* ln_g   = (const float*)d_in[6];
    const float* ln_b   = (const float*)d_in[7];
    const float* Wip    = (const float*)d_in[8];
    const float* w1     = (const float*)d_in[9];
    const float* b1     = (const float*)d_in[10];
    const float* Wxp    = (const float*)d_in[11];
    const float* Wdt    = (const float*)d_in[12];
    const float* bdt    = (const float*)d_in[13];
    const float* A_log  = (const float*)d_in[14];
    const float* Dp     = (const float*)d_in[15];
    const float* Wout   = (const float*)d_in[16];
    const float* dw     = (const float*)d_in[17];

    float* ws = (float*)d_ws;
    size_t o = 0;
    float* y_raw = ws + o; o += (size_t)B_ * 96 * L_;
    float* bnsum = ws + o; o += 96;
    float* bnsq  = ws + o; o += 96;
    float* scale = ws + o; o += 96;
    float* shift = ws + o; o += 96;
    float* xs_t  = ws + o; o += (size_t)B_ * DI_ * L_;
    float* z_t   = ws + o; o += (size_t)B_ * DI_ * L_;
    float* xss_t = ws + o; o += (size_t)B_ * DI_ * L_;
    float* dt_t  = ws + o; o += (size_t)B_ * DI_ * L_;
    float* Bm    = ws + o; o += (size_t)B_ * L_ * DS_;
    float* Cm    = ws + o; o += (size_t)B_ * L_ * DS_;
    float* hpart = ws + o; o += (size_t)NCH_ * B_ * DI_ * DS_;
    float* Pprod = ws + o; o += (size_t)NCH_ * B_ * DI_ * DS_;
    float* H0    = ws + o; o += (size_t)NCH_ * B_ * DI_ * DS_;
    float* g_t   = xs_t;   // xs_t is dead after K4 -> reuse for gated output

    hipMemsetAsync(bnsum, 0, 2 * 96 * sizeof(float), stream);

    k1_conv_bn<<<B_ * 96 * 16, 256, 0, stream>>>(x1, x2, conv_w, conv_b, y_raw, bnsum, bnsq);
    k2_bn_fin<<<1, 128, 0, stream>>>(bnsum, bnsq, bn_g, bn_b, scale, shift);
    k3_ln_inproj<<<B_ * 256, 256, 0, stream>>>(x2, ln_g, ln_b, Wip, xs_t, z_t);
    k4_conv1d_xproj<<<B_ * 256, 256, 0, stream>>>(xs_t, w1, b1, Wxp, Wdt, bdt, xss_t, dt_t, Bm, Cm);
    k5_scan_partial<<<(B_ * DI_ * DS_ * NCH_) / 256, 256, 0, stream>>>(dt_t, xss_t, Bm, A_log, hpart, Pprod);
    k6_combine<<<(B_ * DI_ * DS_) / 256, 256, 0, stream>>>(hpart, Pprod, H0);
    k7_scan_final<<<(B_ * DI_ * DS_ * NCH_) / 256, 256, 0, stream>>>(dt_t, xss_t, Bm, Cm, z_t, A_log, Dp, H0, g_t);
    k8_out<<<B_ * 256, 256, 0, stream>>>(g_t, Wout, y_raw, scale, shift, dw, (float*)d_out);
}